// Round 1
// baseline (2868.626 us; speedup 1.0000x reference)
//
#include <hip/hip_runtime.h>

typedef __bf16 bf16x8 __attribute__((ext_vector_type(8)));
typedef float f32x4 __attribute__((ext_vector_type(4)));

// ---------- helpers ----------
__device__ __forceinline__ unsigned short f2bf(float f) {
  // round-to-nearest-even fp32 -> bf16
  unsigned u = __float_as_uint(f);
  u += 0x7FFFu + ((u >> 16) & 1u);
  return (unsigned short)(u >> 16);
}

__device__ __forceinline__ void async16(const void* g, void* l) {
  // global -> LDS direct copy, 16B per lane; LDS dest = wave-uniform base + lane*16
  __builtin_amdgcn_global_load_lds((const __attribute__((address_space(1))) void*)g,
                                   (__attribute__((address_space(3))) void*)l,
                                   16, 0, 0);
}

// ---------- conversion kernels ----------
__global__ void cvt_f32_bf16_k(const float4* __restrict__ in, ushort4* __restrict__ out) {
  int i = blockIdx.x * blockDim.x + threadIdx.x;
  float4 v = in[i];
  ushort4 o;
  o.x = f2bf(v.x); o.y = f2bf(v.y); o.z = f2bf(v.z); o.w = f2bf(v.w);
  out[i] = o;
}

__global__ void cvt_i32_bf16_k(const int4* __restrict__ in, ushort4* __restrict__ out) {
  int i = blockIdx.x * blockDim.x + threadIdx.x;
  int4 v = in[i];
  ushort4 o;
  o.x = f2bf((float)v.x); o.y = f2bf((float)v.y);
  o.z = f2bf((float)v.z); o.w = f2bf((float)v.w);  // |v|<=128: exact in bf16
  out[i] = o;
}

// ---------- fused gate+up GEMM with SwiGLU epilogue ----------
// C tile 128(M) x 64(N), BK=32, 4 waves each computing 64x32 (4x2 frags) for BOTH gate and up.
// A:[M,K] bf16 row-major, Bg/Bu:[N,K] bf16 row-major (B^T gemm). Hout:[M,N] bf16.
__global__ __launch_bounds__(256)
void gemm_gateup(const unsigned short* __restrict__ A,
                 const unsigned short* __restrict__ Bg,
                 const unsigned short* __restrict__ Bu,
                 const float* __restrict__ gsc, const float* __restrict__ usc,
                 unsigned short* __restrict__ Hout,
                 int M, int N, int K) {
  __shared__ unsigned short sA[128 * 32];
  __shared__ unsigned short sBg[64 * 32];
  __shared__ unsigned short sBu[64 * 32];

  const int tid  = threadIdx.x;
  const int lane = tid & 63;
  const int wv   = tid >> 6;           // 0..3
  const int bN   = blockIdx.x * 64;
  const int bM   = blockIdx.y * 128;

  // staging: lane -> (row = lane>>2, 16B chunk = lane&3) within a 16-row / 64B-row group
  const int lrow = lane >> 2;
  const int lcol = (lane & 3) * 8;     // element offset (8 bf16 = 16B)

  const unsigned short* gA0 = A  + (size_t)(bM + wv * 32 +  0 + lrow) * K + lcol;
  const unsigned short* gA1 = A  + (size_t)(bM + wv * 32 + 16 + lrow) * K + lcol;
  const unsigned short* gB0 = Bg + (size_t)(bN + wv * 16 + lrow) * K + lcol;
  const unsigned short* gB1 = Bu + (size_t)(bN + wv * 16 + lrow) * K + lcol;
  unsigned short* lA0 = &sA [(wv * 32 +  0) * 32];
  unsigned short* lA1 = &sA [(wv * 32 + 16) * 32];
  unsigned short* lB0 = &sBg[(wv * 16) * 32];
  unsigned short* lB1 = &sBu[(wv * 16) * 32];

  const int r = lane & 15;             // m (A) / n (B) within 16-tile
  const int q = lane >> 4;             // k-group: k = q*8 + j
  const int wm = (wv >> 1) * 64;       // wave's m offset in block tile
  const int wn = (wv & 1) * 32;        // wave's n offset in block tile

  f32x4 accg[4][2], accu[4][2];
#pragma unroll
  for (int i = 0; i < 4; i++)
#pragma unroll
    for (int j = 0; j < 2; j++) {
      accg[i][j] = f32x4{0.f, 0.f, 0.f, 0.f};
      accu[i][j] = f32x4{0.f, 0.f, 0.f, 0.f};
    }

  for (int k0 = 0; k0 < K; k0 += 32) {
    async16(gA0 + k0, lA0);
    async16(gA1 + k0, lA1);
    async16(gB0 + k0, lB0);
    async16(gB1 + k0, lB1);
    __syncthreads();   // vmcnt(0) drain before barrier makes staged data visible

    bf16x8 af[4];
#pragma unroll
    for (int mi = 0; mi < 4; mi++)
      af[mi] = *(const bf16x8*)&sA[(wm + mi * 16 + r) * 32 + q * 8];
#pragma unroll
    for (int ni = 0; ni < 2; ni++) {
      bf16x8 bg = *(const bf16x8*)&sBg[(wn + ni * 16 + r) * 32 + q * 8];
      bf16x8 bu = *(const bf16x8*)&sBu[(wn + ni * 16 + r) * 32 + q * 8];
#pragma unroll
      for (int mi = 0; mi < 4; mi++) {
        accg[mi][ni] = __builtin_amdgcn_mfma_f32_16x16x32_bf16(af[mi], bg, accg[mi][ni], 0, 0, 0);
        accu[mi][ni] = __builtin_amdgcn_mfma_f32_16x16x32_bf16(af[mi], bu, accu[mi][ni], 0, 0, 0);
      }
    }
    __syncthreads();   // all reads done before next stage overwrites
  }

  // epilogue: scale, SwiGLU, store bf16. D layout: col=lane&15, row=q*4+rr
#pragma unroll
  for (int ni = 0; ni < 2; ni++) {
    const int col = bN + wn + ni * 16 + r;
    const float gs = gsc[col], us = usc[col];
#pragma unroll
    for (int mi = 0; mi < 4; mi++) {
#pragma unroll
      for (int rr = 0; rr < 4; rr++) {
        const int row = bM + wm + mi * 16 + q * 4 + rr;
        float g = accg[mi][ni][rr] * gs;
        float u = accu[mi][ni][rr] * us;
        float hv = (g / (1.f + __expf(-g))) * u;   // silu(g)*u
        Hout[(size_t)row * N + col] = f2bf(hv);
      }
    }
  }
}

// ---------- down GEMM (single B) with per-col scale epilogue ----------
// C tile 128x128, BK=32, 4 waves each 64x64 (4x4 frags). out fp32.
__global__ __launch_bounds__(256)
void gemm_down(const unsigned short* __restrict__ A,
               const unsigned short* __restrict__ B,
               const float* __restrict__ dsc,
               float* __restrict__ out,
               int M, int N, int K) {
  __shared__ unsigned short sA[128 * 32];
  __shared__ unsigned short sB[128 * 32];

  const int tid  = threadIdx.x;
  const int lane = tid & 63;
  const int wv   = tid >> 6;
  const int bN   = blockIdx.x * 128;
  const int bM   = blockIdx.y * 128;

  const int lrow = lane >> 2;
  const int lcol = (lane & 3) * 8;

  const unsigned short* gA0 = A + (size_t)(bM + wv * 32 +  0 + lrow) * K + lcol;
  const unsigned short* gA1 = A + (size_t)(bM + wv * 32 + 16 + lrow) * K + lcol;
  const unsigned short* gB0 = B + (size_t)(bN + wv * 32 +  0 + lrow) * K + lcol;
  const unsigned short* gB1 = B + (size_t)(bN + wv * 32 + 16 + lrow) * K + lcol;
  unsigned short* lA0 = &sA[(wv * 32 +  0) * 32];
  unsigned short* lA1 = &sA[(wv * 32 + 16) * 32];
  unsigned short* lB0 = &sB[(wv * 32 +  0) * 32];
  unsigned short* lB1 = &sB[(wv * 32 + 16) * 32];

  const int r = lane & 15;
  const int q = lane >> 4;
  const int wm = (wv >> 1) * 64;
  const int wn = (wv & 1) * 64;

  f32x4 acc[4][4];
#pragma unroll
  for (int i = 0; i < 4; i++)
#pragma unroll
    for (int j = 0; j < 4; j++) acc[i][j] = f32x4{0.f, 0.f, 0.f, 0.f};

  for (int k0 = 0; k0 < K; k0 += 32) {
    async16(gA0 + k0, lA0);
    async16(gA1 + k0, lA1);
    async16(gB0 + k0, lB0);
    async16(gB1 + k0, lB1);
    __syncthreads();

    bf16x8 af[4];
#pragma unroll
    for (int mi = 0; mi < 4; mi++)
      af[mi] = *(const bf16x8*)&sA[(wm + mi * 16 + r) * 32 + q * 8];
#pragma unroll
    for (int ni = 0; ni < 4; ni++) {
      bf16x8 bf = *(const bf16x8*)&sB[(wn + ni * 16 + r) * 32 + q * 8];
#pragma unroll
      for (int mi = 0; mi < 4; mi++)
        acc[mi][ni] = __builtin_amdgcn_mfma_f32_16x16x32_bf16(af[mi], bf, acc[mi][ni], 0, 0, 0);
    }
    __syncthreads();
  }

#pragma unroll
  for (int ni = 0; ni < 4; ni++) {
    const int col = bN + wn + ni * 16 + r;
    const float s = dsc[col];
#pragma unroll
    for (int mi = 0; mi < 4; mi++) {
#pragma unroll
      for (int rr = 0; rr < 4; rr++) {
        const int row = bM + wm + mi * 16 + q * 4 + rr;
        out[(size_t)row * N + col] = acc[mi][ni][rr] * s;
      }
    }
  }
}

// ---------- launch ----------
extern "C" void kernel_launch(void* const* d_in, const int* in_sizes, int n_in,
                              void* d_out, int out_size, void* d_ws, size_t ws_size,
                              hipStream_t stream) {
  constexpr int M  = 4096;   // B*S
  constexpr int Hd = 4096;   // hidden
  constexpr int Id = 14336;  // intermediate

  const float* x   = (const float*)d_in[0];
  const int*   gwq = (const int*)  d_in[1];
  const float* gsc = (const float*)d_in[2];
  const int*   uwq = (const int*)  d_in[3];
  const float* usc = (const float*)d_in[4];
  const int*   dwq = (const int*)  d_in[5];
  const float* dsc = (const float*)d_in[6];
  float* out = (float*)d_out;

  // ws layout (bf16/ushort elems): xb | w0 (gate, later down) | wu | h  = 368 MiB total
  unsigned short* xb = (unsigned short*)d_ws;
  unsigned short* w0 = xb + (size_t)M * Hd;            // 16,777,216 elems
  unsigned short* wu = w0 + (size_t)Id * Hd;           // +58,720,256
  unsigned short* hb = wu + (size_t)Id * Hd;           // +58,720,256 (M*Id elems)

  // conversions: x fp32->bf16 (RNE), weights int32->bf16 (exact)
  cvt_f32_bf16_k<<<(M * Hd) / 1024, 256, 0, stream>>>((const float4*)x, (ushort4*)xb);
  cvt_i32_bf16_k<<<((size_t)Id * Hd) / 1024, 256, 0, stream>>>((const int4*)gwq, (ushort4*)w0);
  cvt_i32_bf16_k<<<((size_t)Id * Hd) / 1024, 256, 0, stream>>>((const int4*)uwq, (ushort4*)wu);

  // fused gate+up + SwiGLU -> h (bf16)
  gemm_gateup<<<dim3(Id / 64, M / 128), 256, 0, stream>>>(xb, w0, wu, gsc, usc, hb, M, Id, Hd);

  // reuse w0 region for down weights
  cvt_i32_bf16_k<<<((size_t)Hd * Id) / 1024, 256, 0, stream>>>((const int4*)dwq, (ushort4*)w0);

  // down GEMM -> fp32 out
  gemm_down<<<dim3(Hd / 128, M / 128), 256, 0, stream>>>(hb, w0, dsc, out, M, Hd, Id);
}

// Round 2
// 2466.908 us; speedup vs baseline: 1.1628x; 1.1628x over previous
//
#include <hip/hip_runtime.h>

typedef __bf16 bf16x8 __attribute__((ext_vector_type(8)));
typedef float f32x4 __attribute__((ext_vector_type(4)));

// ---------- helpers ----------
__device__ __forceinline__ unsigned short f2bf(float f) {
  // round-to-nearest-even fp32 -> bf16
  unsigned u = __float_as_uint(f);
  u += 0x7FFFu + ((u >> 16) & 1u);
  return (unsigned short)(u >> 16);
}

__device__ __forceinline__ void async16(const void* g, void* l) {
  // global -> LDS direct copy, 16B/lane; LDS dest = wave-uniform base + lane*16
  __builtin_amdgcn_global_load_lds((const __attribute__((address_space(1))) void*)g,
                                   (__attribute__((address_space(3))) void*)l,
                                   16, 0, 0);
}

// ---------- conversion kernels ----------
__global__ void cvt_f32_bf16_k(const float4* __restrict__ in, ushort4* __restrict__ out) {
  int i = blockIdx.x * blockDim.x + threadIdx.x;
  float4 v = in[i];
  ushort4 o;
  o.x = f2bf(v.x); o.y = f2bf(v.y); o.z = f2bf(v.z); o.w = f2bf(v.w);
  out[i] = o;
}

__global__ void cvt_i32_bf16_k(const int4* __restrict__ in, ushort4* __restrict__ out) {
  int i = blockIdx.x * blockDim.x + threadIdx.x;
  int4 v = in[i];
  ushort4 o;
  o.x = f2bf((float)v.x); o.y = f2bf((float)v.y);
  o.z = f2bf((float)v.z); o.w = f2bf((float)v.w);  // |v|<=128: exact in bf16
  out[i] = o;
}

// ---------- fused gate+up GEMM with SwiGLU epilogue ----------
// C tile 128(M) x 64(N) for BOTH gate & up; BK=64; XOR-swizzled LDS (16B chunk ^ row&7)
// so ds_read_b128 is 2-way (free) instead of 8-way banked.
__global__ __launch_bounds__(256)
void gemm_gateup(const unsigned short* __restrict__ A,
                 const unsigned short* __restrict__ Bg,
                 const unsigned short* __restrict__ Bu,
                 const float* __restrict__ gsc, const float* __restrict__ usc,
                 unsigned short* __restrict__ Hout,
                 int M, int N, int K) {
  __shared__ unsigned short sA[128 * 64];
  __shared__ unsigned short sBg[64 * 64];
  __shared__ unsigned short sBu[64 * 64];

  const int tid  = threadIdx.x;
  const int lane = tid & 63;
  const int wv   = tid >> 6;           // 0..3
  const int bN   = blockIdx.x * 64;
  const int bM   = blockIdx.y * 128;

  // staging: each async16 covers 8 rows x 128B. lane -> row=lane>>3, phys chunk=lane&7.
  // stored logical chunk = phys ^ (row&7); row&7 == lane>>3 for 8-aligned row groups,
  // so the per-lane global column offset is constant across calls:
  const int srow = lane >> 3;                    // 0..7
  const int gcol = ((lane & 7) ^ srow) * 8;      // element offset of the 16B chunk

  const unsigned short* gA  = A  + (size_t)(bM + wv * 32 + srow) * K + gcol;
  const unsigned short* gBg = Bg + (size_t)(bN + wv * 16 + srow) * K + gcol;
  const unsigned short* gBu = Bu + (size_t)(bN + wv * 16 + srow) * K + gcol;
  unsigned short* lA  = &sA [(wv * 32) * 64];
  unsigned short* lBg = &sBg[(wv * 16) * 64];
  unsigned short* lBu = &sBu[(wv * 16) * 64];

  const int r = lane & 15;             // m (A) / n (B) within 16-tile
  const int q = lane >> 4;             // k-group: k = q*8 + j
  const int rx = r & 7;                // read-side swizzle term (row&7 == r&7)
  const int wm = (wv >> 1) * 64;       // wave's m offset in block tile
  const int wn = (wv & 1) * 32;        // wave's n offset in block tile

  f32x4 accg[4][2], accu[4][2];
#pragma unroll
  for (int i = 0; i < 4; i++)
#pragma unroll
    for (int j = 0; j < 2; j++) {
      accg[i][j] = f32x4{0.f, 0.f, 0.f, 0.f};
      accu[i][j] = f32x4{0.f, 0.f, 0.f, 0.f};
    }

  for (int k0 = 0; k0 < K; k0 += 64) {
    const unsigned short* pA = gA + k0;
    async16(pA,                  lA);
    async16(pA +  8 * (size_t)K, lA +  8 * 64);
    async16(pA + 16 * (size_t)K, lA + 16 * 64);
    async16(pA + 24 * (size_t)K, lA + 24 * 64);
    const unsigned short* pG = gBg + k0;
    async16(pG,                  lBg);
    async16(pG +  8 * (size_t)K, lBg + 8 * 64);
    const unsigned short* pU = gBu + k0;
    async16(pU,                  lBu);
    async16(pU +  8 * (size_t)K, lBu + 8 * 64);
    __syncthreads();

#pragma unroll
    for (int kk = 0; kk < 2; ++kk) {
      const int pc = ((kk * 4 + q) ^ rx) * 8;   // physical chunk offset (elems)
      bf16x8 af[4];
#pragma unroll
      for (int mi = 0; mi < 4; mi++)
        af[mi] = *(const bf16x8*)&sA[(wm + mi * 16 + r) * 64 + pc];
#pragma unroll
      for (int ni = 0; ni < 2; ni++) {
        bf16x8 bg = *(const bf16x8*)&sBg[(wn + ni * 16 + r) * 64 + pc];
        bf16x8 bu = *(const bf16x8*)&sBu[(wn + ni * 16 + r) * 64 + pc];
#pragma unroll
        for (int mi = 0; mi < 4; mi++) {
          accg[mi][ni] = __builtin_amdgcn_mfma_f32_16x16x32_bf16(af[mi], bg, accg[mi][ni], 0, 0, 0);
          accu[mi][ni] = __builtin_amdgcn_mfma_f32_16x16x32_bf16(af[mi], bu, accu[mi][ni], 0, 0, 0);
        }
      }
    }
    __syncthreads();
  }

  // epilogue: scale, SwiGLU, store bf16. D layout: col=lane&15, row=q*4+rr
#pragma unroll
  for (int ni = 0; ni < 2; ni++) {
    const int col = bN + wn + ni * 16 + r;
    const float gs = gsc[col], us = usc[col];
#pragma unroll
    for (int mi = 0; mi < 4; mi++) {
#pragma unroll
      for (int rr = 0; rr < 4; rr++) {
        const int row = bM + wm + mi * 16 + q * 4 + rr;
        float g = accg[mi][ni][rr] * gs;
        float u = accu[mi][ni][rr] * us;
        float hv = (g / (1.f + __expf(-g))) * u;   // silu(g)*u
        Hout[(size_t)row * N + col] = f2bf(hv);
      }
    }
  }
}

// ---------- down GEMM (single B) with per-col scale epilogue ----------
// C tile 128x128, BK=64, same XOR-swizzled LDS. out fp32.
__global__ __launch_bounds__(256)
void gemm_down(const unsigned short* __restrict__ A,
               const unsigned short* __restrict__ B,
               const float* __restrict__ dsc,
               float* __restrict__ out,
               int M, int N, int K) {
  __shared__ unsigned short sA[128 * 64];
  __shared__ unsigned short sB[128 * 64];

  const int tid  = threadIdx.x;
  const int lane = tid & 63;
  const int wv   = tid >> 6;
  const int bN   = blockIdx.x * 128;
  const int bM   = blockIdx.y * 128;

  const int srow = lane >> 3;
  const int gcol = ((lane & 7) ^ srow) * 8;

  const unsigned short* gA = A + (size_t)(bM + wv * 32 + srow) * K + gcol;
  const unsigned short* gB = B + (size_t)(bN + wv * 32 + srow) * K + gcol;
  unsigned short* lA = &sA[(wv * 32) * 64];
  unsigned short* lB = &sB[(wv * 32) * 64];

  const int r = lane & 15;
  const int q = lane >> 4;
  const int rx = r & 7;
  const int wm = (wv >> 1) * 64;
  const int wn = (wv & 1) * 64;

  f32x4 acc[4][4];
#pragma unroll
  for (int i = 0; i < 4; i++)
#pragma unroll
    for (int j = 0; j < 4; j++) acc[i][j] = f32x4{0.f, 0.f, 0.f, 0.f};

  for (int k0 = 0; k0 < K; k0 += 64) {
    const unsigned short* pA = gA + k0;
    async16(pA,                  lA);
    async16(pA +  8 * (size_t)K, lA +  8 * 64);
    async16(pA + 16 * (size_t)K, lA + 16 * 64);
    async16(pA + 24 * (size_t)K, lA + 24 * 64);
    const unsigned short* pB = gB + k0;
    async16(pB,                  lB);
    async16(pB +  8 * (size_t)K, lB +  8 * 64);
    async16(pB + 16 * (size_t)K, lB + 16 * 64);
    async16(pB + 24 * (size_t)K, lB + 24 * 64);
    __syncthreads();

#pragma unroll
    for (int kk = 0; kk < 2; ++kk) {
      const int pc = ((kk * 4 + q) ^ rx) * 8;
      bf16x8 af[4];
#pragma unroll
      for (int mi = 0; mi < 4; mi++)
        af[mi] = *(const bf16x8*)&sA[(wm + mi * 16 + r) * 64 + pc];
#pragma unroll
      for (int ni = 0; ni < 4; ni++) {
        bf16x8 bfr = *(const bf16x8*)&sB[(wn + ni * 16 + r) * 64 + pc];
#pragma unroll
        for (int mi = 0; mi < 4; mi++)
          acc[mi][ni] = __builtin_amdgcn_mfma_f32_16x16x32_bf16(af[mi], bfr, acc[mi][ni], 0, 0, 0);
      }
    }
    __syncthreads();
  }

#pragma unroll
  for (int ni = 0; ni < 4; ni++) {
    const int col = bN + wn + ni * 16 + r;
    const float s = dsc[col];
#pragma unroll
    for (int mi = 0; mi < 4; mi++) {
#pragma unroll
      for (int rr = 0; rr < 4; rr++) {
        const int row = bM + wm + mi * 16 + q * 4 + rr;
        out[(size_t)row * N + col] = acc[mi][ni][rr] * s;
      }
    }
  }
}

// ---------- launch ----------
extern "C" void kernel_launch(void* const* d_in, const int* in_sizes, int n_in,
                              void* d_out, int out_size, void* d_ws, size_t ws_size,
                              hipStream_t stream) {
  constexpr int M  = 4096;   // B*S
  constexpr int Hd = 4096;   // hidden
  constexpr int Id = 14336;  // intermediate

  const float* x   = (const float*)d_in[0];
  const int*   gwq = (const int*)  d_in[1];
  const float* gsc = (const float*)d_in[2];
  const int*   uwq = (const int*)  d_in[3];
  const float* usc = (const float*)d_in[4];
  const int*   dwq = (const int*)  d_in[5];
  const float* dsc = (const float*)d_in[6];
  float* out = (float*)d_out;

  // ws layout (bf16/ushort elems): xb | w0 (gate, later down) | wu | h  = 368 MiB total
  unsigned short* xb = (unsigned short*)d_ws;
  unsigned short* w0 = xb + (size_t)M * Hd;
  unsigned short* wu = w0 + (size_t)Id * Hd;
  unsigned short* hb = wu + (size_t)Id * Hd;

  // conversions: x fp32->bf16 (RNE), weights int32->bf16 (exact)
  cvt_f32_bf16_k<<<(M * Hd) / 1024, 256, 0, stream>>>((const float4*)x, (ushort4*)xb);
  cvt_i32_bf16_k<<<((size_t)Id * Hd) / 1024, 256, 0, stream>>>((const int4*)gwq, (ushort4*)w0);
  cvt_i32_bf16_k<<<((size_t)Id * Hd) / 1024, 256, 0, stream>>>((const int4*)uwq, (ushort4*)wu);

  // fused gate+up + SwiGLU -> h (bf16)
  gemm_gateup<<<dim3(Id / 64, M / 128), 256, 0, stream>>>(xb, w0, wu, gsc, usc, hb, M, Id, Hd);

  // reuse w0 region for down weights
  cvt_i32_bf16_k<<<((size_t)Hd * Id) / 1024, 256, 0, stream>>>((const int4*)dwq, (ushort4*)w0);

  // down GEMM -> fp32 out
  gemm_down<<<dim3(Hd / 128, M / 128), 256, 0, stream>>>(hb, w0, dsc, out, M, Hd, Id);
}

// Round 3
// 2219.746 us; speedup vs baseline: 1.2923x; 1.1113x over previous
//
#include <hip/hip_runtime.h>

typedef __bf16 bf16x8 __attribute__((ext_vector_type(8)));
typedef float f32x4 __attribute__((ext_vector_type(4)));

// ---------- helpers ----------
__device__ __forceinline__ unsigned short f2bf(float f) {
  unsigned u = __float_as_uint(f);
  u += 0x7FFFu + ((u >> 16) & 1u);
  return (unsigned short)(u >> 16);
}

__device__ __forceinline__ void async16(const void* g, void* l) {
  // global -> LDS direct copy, 16B/lane; LDS dest = wave-uniform base + lane*16
  __builtin_amdgcn_global_load_lds((const __attribute__((address_space(1))) void*)g,
                                   (__attribute__((address_space(3))) void*)l,
                                   16, 0, 0);
}

// ---------- conversion kernels ----------
__global__ void cvt_f32_bf16_k(const float4* __restrict__ in, ushort4* __restrict__ out) {
  int i = blockIdx.x * blockDim.x + threadIdx.x;
  float4 v = in[i];
  ushort4 o;
  o.x = f2bf(v.x); o.y = f2bf(v.y); o.z = f2bf(v.z); o.w = f2bf(v.w);
  out[i] = o;
}

__global__ void cvt_i32_bf16_k(const int4* __restrict__ in, ushort4* __restrict__ out) {
  int i = blockIdx.x * blockDim.x + threadIdx.x;
  int4 v = in[i];
  ushort4 o;
  o.x = f2bf((float)v.x); o.y = f2bf((float)v.y);
  o.z = f2bf((float)v.z); o.w = f2bf((float)v.w);  // |v|<=128: exact in bf16
  out[i] = o;
}

// ---------- fused gate+up GEMM with SwiGLU epilogue ----------
// Block tile 128(M) x 128(N), BK=64; wave tile 64x64 dual (gate+up) 4x4 frags.
// XOR-swizzled LDS (16B chunk ^ row&7): ds_read_b128 2-way = conflict-free.
// Grouped launch order: 8 N-tiles x all M-tiles per group -> B weights stream
// HBM once, A + B-chunk stay L2/LLC resident.
__global__ __launch_bounds__(256, 2)
void gemm_gateup(const unsigned short* __restrict__ A,
                 const unsigned short* __restrict__ Bg,
                 const unsigned short* __restrict__ Bu,
                 const float* __restrict__ gsc, const float* __restrict__ usc,
                 unsigned short* __restrict__ Hout,
                 int M, int N, int K) {
  __shared__ unsigned short sA[128 * 64];
  __shared__ unsigned short sBg[128 * 64];
  __shared__ unsigned short sBu[128 * 64];

  const int tid  = threadIdx.x;
  const int lane = tid & 63;
  const int wv   = tid >> 6;           // 0..3

  // grouped ordering: NN=112 n-tiles, MM=32 m-tiles, GN=8 -> 256 blocks/group
  const int bid = blockIdx.x;
  const int grp = bid >> 8;            // /256
  const int rem = bid & 255;
  const int bN  = ((grp << 3) + (rem & 7)) * 128;
  const int bM  = (rem >> 3) * 128;

  // staging: async16 covers 8 rows x 128B; lane row=lane>>3, phys chunk=lane&7;
  // logical chunk = phys ^ (row&7) -> constant per-lane global offset:
  const int srow = lane >> 3;                    // 0..7
  const int gcol = ((lane & 7) ^ srow) * 8;      // element offset of 16B chunk

  const unsigned short* gA  = A  + (size_t)(bM + wv * 32 + srow) * K + gcol;
  const unsigned short* gBg = Bg + (size_t)(bN + wv * 32 + srow) * K + gcol;
  const unsigned short* gBu = Bu + (size_t)(bN + wv * 32 + srow) * K + gcol;
  unsigned short* lA  = &sA [(wv * 32) * 64];
  unsigned short* lBg = &sBg[(wv * 32) * 64];
  unsigned short* lBu = &sBu[(wv * 32) * 64];

  const int r  = lane & 15;            // m (A) / n (B) within 16-tile
  const int q  = lane >> 4;            // k-group
  const int rx = r & 7;                // read-side swizzle term
  const int wm = (wv >> 1) * 64;
  const int wn = (wv & 1) * 64;

  f32x4 accg[4][4], accu[4][4];
#pragma unroll
  for (int i = 0; i < 4; i++)
#pragma unroll
    for (int j = 0; j < 4; j++) {
      accg[i][j] = f32x4{0.f, 0.f, 0.f, 0.f};
      accu[i][j] = f32x4{0.f, 0.f, 0.f, 0.f};
    }

  for (int k0 = 0; k0 < K; k0 += 64) {
    const unsigned short* pA = gA + k0;
    async16(pA,                  lA);
    async16(pA +  8 * (size_t)K, lA +  8 * 64);
    async16(pA + 16 * (size_t)K, lA + 16 * 64);
    async16(pA + 24 * (size_t)K, lA + 24 * 64);
    const unsigned short* pG = gBg + k0;
    async16(pG,                  lBg);
    async16(pG +  8 * (size_t)K, lBg +  8 * 64);
    async16(pG + 16 * (size_t)K, lBg + 16 * 64);
    async16(pG + 24 * (size_t)K, lBg + 24 * 64);
    const unsigned short* pU = gBu + k0;
    async16(pU,                  lBu);
    async16(pU +  8 * (size_t)K, lBu +  8 * 64);
    async16(pU + 16 * (size_t)K, lBu + 16 * 64);
    async16(pU + 24 * (size_t)K, lBu + 24 * 64);
    __syncthreads();

#pragma unroll
    for (int kk = 0; kk < 2; ++kk) {
      const int pc = ((kk * 4 + q) ^ rx) * 8;   // physical chunk offset (elems)
      bf16x8 af[4];
#pragma unroll
      for (int mi = 0; mi < 4; mi++)
        af[mi] = *(const bf16x8*)&sA[(wm + mi * 16 + r) * 64 + pc];
#pragma unroll
      for (int ni = 0; ni < 4; ni++) {
        bf16x8 bg = *(const bf16x8*)&sBg[(wn + ni * 16 + r) * 64 + pc];
        bf16x8 bu = *(const bf16x8*)&sBu[(wn + ni * 16 + r) * 64 + pc];
#pragma unroll
        for (int mi = 0; mi < 4; mi++) {
          accg[mi][ni] = __builtin_amdgcn_mfma_f32_16x16x32_bf16(af[mi], bg, accg[mi][ni], 0, 0, 0);
          accu[mi][ni] = __builtin_amdgcn_mfma_f32_16x16x32_bf16(af[mi], bu, accu[mi][ni], 0, 0, 0);
        }
      }
    }
    __syncthreads();
  }

  // epilogue: scale, SwiGLU, store bf16. D layout: col=lane&15, row=q*4+rr
#pragma unroll
  for (int ni = 0; ni < 4; ni++) {
    const int col = bN + wn + ni * 16 + r;
    const float gs = gsc[col], us = usc[col];
#pragma unroll
    for (int mi = 0; mi < 4; mi++) {
#pragma unroll
      for (int rr = 0; rr < 4; rr++) {
        const int row = bM + wm + mi * 16 + q * 4 + rr;
        float g = accg[mi][ni][rr] * gs;
        float u = accu[mi][ni][rr] * us;
        float hv = (g / (1.f + __expf(-g))) * u;   // silu(g)*u
        Hout[(size_t)row * N + col] = f2bf(hv);
      }
    }
  }
}

// ---------- down GEMM (single B) with per-col scale epilogue ----------
// C tile 128x128, BK=64, XOR-swizzled LDS, grouped launch (16x16 super-tiles).
__global__ __launch_bounds__(256)
void gemm_down(const unsigned short* __restrict__ A,
               const unsigned short* __restrict__ B,
               const float* __restrict__ dsc,
               float* __restrict__ out,
               int M, int N, int K) {
  __shared__ unsigned short sA[128 * 64];
  __shared__ unsigned short sB[128 * 64];

  const int tid  = threadIdx.x;
  const int lane = tid & 63;
  const int wv   = tid >> 6;

  // grouped ordering: NN=32, MM=32, 1024 blocks; 16 N x 32 M per group (512)
  const int bid = blockIdx.x;
  const int grp = bid >> 9;
  const int rem = bid & 511;
  const int bN  = ((grp << 4) + (rem & 15)) * 128;
  const int bM  = (rem >> 4) * 128;

  const int srow = lane >> 3;
  const int gcol = ((lane & 7) ^ srow) * 8;

  const unsigned short* gA = A + (size_t)(bM + wv * 32 + srow) * K + gcol;
  const unsigned short* gB = B + (size_t)(bN + wv * 32 + srow) * K + gcol;
  unsigned short* lA = &sA[(wv * 32) * 64];
  unsigned short* lB = &sB[(wv * 32) * 64];

  const int r  = lane & 15;
  const int q  = lane >> 4;
  const int rx = r & 7;
  const int wm = (wv >> 1) * 64;
  const int wn = (wv & 1) * 64;

  f32x4 acc[4][4];
#pragma unroll
  for (int i = 0; i < 4; i++)
#pragma unroll
    for (int j = 0; j < 4; j++) acc[i][j] = f32x4{0.f, 0.f, 0.f, 0.f};

  for (int k0 = 0; k0 < K; k0 += 64) {
    const unsigned short* pA = gA + k0;
    async16(pA,                  lA);
    async16(pA +  8 * (size_t)K, lA +  8 * 64);
    async16(pA + 16 * (size_t)K, lA + 16 * 64);
    async16(pA + 24 * (size_t)K, lA + 24 * 64);
    const unsigned short* pB = gB + k0;
    async16(pB,                  lB);
    async16(pB +  8 * (size_t)K, lB +  8 * 64);
    async16(pB + 16 * (size_t)K, lB + 16 * 64);
    async16(pB + 24 * (size_t)K, lB + 24 * 64);
    __syncthreads();

#pragma unroll
    for (int kk = 0; kk < 2; ++kk) {
      const int pc = ((kk * 4 + q) ^ rx) * 8;
      bf16x8 af[4];
#pragma unroll
      for (int mi = 0; mi < 4; mi++)
        af[mi] = *(const bf16x8*)&sA[(wm + mi * 16 + r) * 64 + pc];
#pragma unroll
      for (int ni = 0; ni < 4; ni++) {
        bf16x8 bfr = *(const bf16x8*)&sB[(wn + ni * 16 + r) * 64 + pc];
#pragma unroll
        for (int mi = 0; mi < 4; mi++)
          acc[mi][ni] = __builtin_amdgcn_mfma_f32_16x16x32_bf16(af[mi], bfr, acc[mi][ni], 0, 0, 0);
      }
    }
    __syncthreads();
  }

#pragma unroll
  for (int ni = 0; ni < 4; ni++) {
    const int col = bN + wn + ni * 16 + r;
    const float s = dsc[col];
#pragma unroll
    for (int mi = 0; mi < 4; mi++) {
#pragma unroll
      for (int rr = 0; rr < 4; rr++) {
        const int row = bM + wm + mi * 16 + q * 4 + rr;
        out[(size_t)row * N + col] = acc[mi][ni][rr] * s;
      }
    }
  }
}

// ---------- launch ----------
extern "C" void kernel_launch(void* const* d_in, const int* in_sizes, int n_in,
                              void* d_out, int out_size, void* d_ws, size_t ws_size,
                              hipStream_t stream) {
  constexpr int M  = 4096;   // B*S
  constexpr int Hd = 4096;   // hidden
  constexpr int Id = 14336;  // intermediate

  const float* x   = (const float*)d_in[0];
  const int*   gwq = (const int*)  d_in[1];
  const float* gsc = (const float*)d_in[2];
  const int*   uwq = (const int*)  d_in[3];
  const float* usc = (const float*)d_in[4];
  const int*   dwq = (const int*)  d_in[5];
  const float* dsc = (const float*)d_in[6];
  float* out = (float*)d_out;

  // ws layout (bf16/ushort elems): xb | w0 (gate, later down) | wu | h
  unsigned short* xb = (unsigned short*)d_ws;
  unsigned short* w0 = xb + (size_t)M * Hd;
  unsigned short* wu = w0 + (size_t)Id * Hd;
  unsigned short* hb = wu + (size_t)Id * Hd;

  cvt_f32_bf16_k<<<(M * Hd) / 1024, 256, 0, stream>>>((const float4*)x, (ushort4*)xb);
  cvt_i32_bf16_k<<<((size_t)Id * Hd) / 1024, 256, 0, stream>>>((const int4*)gwq, (ushort4*)w0);
  cvt_i32_bf16_k<<<((size_t)Id * Hd) / 1024, 256, 0, stream>>>((const int4*)uwq, (ushort4*)wu);

  // fused gate+up + SwiGLU -> h (bf16); grid = 112*32 blocks, grouped internally
  gemm_gateup<<<(Id / 128) * (M / 128), 256, 0, stream>>>(xb, w0, wu, gsc, usc, hb, M, Id, Hd);

  // reuse w0 region for down weights
  cvt_i32_bf16_k<<<((size_t)Hd * Id) / 1024, 256, 0, stream>>>((const int4*)dwq, (ushort4*)w0);

  // down GEMM -> fp32 out; grid = 32*32 blocks, grouped internally
  gemm_down<<<(Hd / 128) * (M / 128), 256, 0, stream>>>(hb, w0, dsc, out, M, Hd, Id);
}